// Round 10
// baseline (616.962 us; speedup 1.0000x reference)
//
#include <hip/hip_runtime.h>
#include <stdint.h>

#define NTOK   4096
#define DM     2048
#define DMLP   8192
#define NEXP   8
#define NRANK  16
#define SCAL   2.0f

// Wide-A strides (LoRA folded into K):
//   xa: [4096, 2304]  = [x_bf16 | SCAL*t_gate_masked(128) | SCAL*t_up_masked(128)]
//   ha: [4096, 8320]  = [h_bf16 | SCAL*t_down_masked(128)]
#define LDXA 2304
#define LDHA 8320

typedef __bf16 bf16x8 __attribute__((ext_vector_type(8)));
typedef float  f32x4  __attribute__((ext_vector_type(4)));
typedef unsigned short u16;

__device__ __forceinline__ u16 f2bf(float f) {
  unsigned u = __float_as_uint(f);
  u += 0x7fffu + ((u >> 16) & 1u);   // RNE
  return (u16)(u >> 16);
}

__device__ __forceinline__ void gload_lds16(const void* g, void* l) {
  __builtin_amdgcn_global_load_lds((const __attribute__((address_space(1))) void*)g,
                                   (__attribute__((address_space(3))) void*)l, 16, 0, 0);
}

// ---------------- fused prep: all f32->bf16 converts + extended weights ----------------
__global__ void prep_kernel(const float* __restrict__ wg, const float* __restrict__ wu,
                            const float* __restrict__ wd,
                            const float* __restrict__ Ag, const float* __restrict__ Au,
                            const float* __restrict__ Ad,
                            const float* __restrict__ Bg, const float* __restrict__ Bu,
                            const float* __restrict__ Bd,
                            u16* __restrict__ wgx, u16* __restrict__ wux,
                            u16* __restrict__ wdx, u16* __restrict__ Aab,
                            u16* __restrict__ Adb) {
  const int gt = blockIdx.x * blockDim.x + threadIdx.x;
  const int gs = gridDim.x * blockDim.x;

  for (int i = gt; i < DMLP * 512; i += gs) {
    const int o = i >> 9, c = (i & 511) << 2;
    float4 v = ((const float4*)wg)[i];
    ushort4 ov; ov.x = f2bf(v.x); ov.y = f2bf(v.y); ov.z = f2bf(v.z); ov.w = f2bf(v.w);
    *(ushort4*)(wgx + (size_t)o * LDXA + c) = ov;
    v = ((const float4*)wu)[i];
    ov.x = f2bf(v.x); ov.y = f2bf(v.y); ov.z = f2bf(v.z); ov.w = f2bf(v.w);
    *(ushort4*)(wux + (size_t)o * LDXA + c) = ov;
  }
  for (int i = gt; i < DM * 2048; i += gs) {
    const int o = i >> 11, c = (i & 2047) << 2;
    float4 v = ((const float4*)wd)[i];
    ushort4 ov; ov.x = f2bf(v.x); ov.y = f2bf(v.y); ov.z = f2bf(v.z); ov.w = f2bf(v.w);
    *(ushort4*)(wdx + (size_t)o * LDHA + c) = ov;
  }
  for (int i = gt; i < 256 * 512; i += gs) {
    float4 v = (i < 128 * 512) ? ((const float4*)Ag)[i] : ((const float4*)Au)[i - 128 * 512];
    ushort4 ov; ov.x = f2bf(v.x); ov.y = f2bf(v.y); ov.z = f2bf(v.z); ov.w = f2bf(v.w);
    ((ushort4*)Aab)[i] = ov;
  }
  for (int i = gt; i < 128 * 2048; i += gs) {
    float4 v = ((const float4*)Ad)[i];
    ushort4 ov; ov.x = f2bf(v.x); ov.y = f2bf(v.y); ov.z = f2bf(v.z); ov.w = f2bf(v.w);
    ((ushort4*)Adb)[i] = ov;
  }
  for (int i = gt; i < DMLP * 256; i += gs) {
    const int o = i >> 8, c = i & 255;
    const int e = (c & 127) >> 4, r = c & 15;
    u16 vg = 0, vu = 0;
    if (c < 128) vg = f2bf(Bg[((size_t)e * DMLP + o) * NRANK + r]);
    else         vu = f2bf(Bu[((size_t)e * DMLP + o) * NRANK + r]);
    wgx[(size_t)o * LDXA + 2048 + c] = vg;
    wux[(size_t)o * LDXA + 2048 + c] = vu;
  }
  for (int i = gt; i < DM * 128; i += gs) {
    const int o = i >> 7, c = i & 127;
    const int e = c >> 4, r = c & 15;
    wdx[(size_t)o * LDHA + 8192 + c] = f2bf(Bd[((size_t)e * DM + o) * NRANK + r]);
  }
}

// ---------------- router ----------------
__global__ void router_kernel(const float* __restrict__ x,
                              const float* __restrict__ rw,
                              const float* __restrict__ rb,
                              u16* __restrict__ xa,
                              int* __restrict__ idx,
                              float* __restrict__ out_rout,
                              float* __restrict__ out_ec) {
  const int wave = threadIdx.x >> 6;
  const int lane = threadIdx.x & 63;
  const int m = blockIdx.x * 4 + wave;

  const float4* xrow = (const float4*)(x + (size_t)m * DM + lane * 32);
  float4 xv[8];
#pragma unroll
  for (int i = 0; i < 8; ++i) xv[i] = xrow[i];

  uint4 o[4];
  unsigned* op = (unsigned*)o;
#pragma unroll
  for (int i = 0; i < 8; ++i) {
    op[2*i]   = (unsigned)f2bf(xv[i].x) | ((unsigned)f2bf(xv[i].y) << 16);
    op[2*i+1] = (unsigned)f2bf(xv[i].z) | ((unsigned)f2bf(xv[i].w) << 16);
  }
  uint4* xdst = (uint4*)(xa + (size_t)m * LDXA + lane * 32);
#pragma unroll
  for (int i = 0; i < 4; ++i) xdst[i] = o[i];

  float lg[NEXP];
#pragma unroll
  for (int e = 0; e < NEXP; ++e) {
    const float4* wrow = (const float4*)(rw + (size_t)e * DM + lane * 32);
    float s = 0.f;
#pragma unroll
    for (int i = 0; i < 8; ++i) {
      float4 wv = wrow[i];
      s += xv[i].x*wv.x + xv[i].y*wv.y + xv[i].z*wv.z + xv[i].w*wv.w;
    }
#pragma unroll
    for (int off = 32; off > 0; off >>= 1) s += __shfl_xor(s, off, 64);
    lg[e] = s + rb[e];
  }

  float mx = lg[0];
#pragma unroll
  for (int e = 1; e < NEXP; ++e) mx = fmaxf(mx, lg[e]);
  float ex[NEXP], se = 0.f;
#pragma unroll
  for (int e = 0; e < NEXP; ++e) { ex[e] = expf(lg[e] - mx); se += ex[e]; }
  float inv = 1.f / se;
  int best = 0; float bv = lg[0];
#pragma unroll
  for (int e = 1; e < NEXP; ++e) if (lg[e] > bv) { bv = lg[e]; best = e; }

  if (lane == 0) {
    idx[m] = best;
#pragma unroll
    for (int e = 0; e < NEXP; ++e) {
      float r = ex[e] * inv;
      out_rout[(size_t)m * NEXP + e] = r;
      float hard = (e == best) ? 1.f : 0.f;
      out_ec[(size_t)m * NEXP + e] = (hard - r) + r;
    }
  }
}

// ---------------- old 128x128 GEMM core (small MODE 0 / MODE 3) ----------------
template<int MODE>
__global__ __launch_bounds__(256, 2)
void gemm_kernel(const u16* __restrict__ A,
                 const u16* __restrict__ B0,
                 const int* __restrict__ idx,
                 void* __restrict__ Cout)
{
  constexpr int LDA = (MODE == 0) ? LDXA : LDHA;
  constexpr int LDB = (MODE == 0) ? 2048 : 8192;
  constexpr int NKI = (MODE == 0) ? 64 : 32;

  __shared__ u16 lds[16384];

  const int tid = threadIdx.x;
  const int w = tid >> 6;
  const int l = tid & 63;
  const int wm = w >> 1, wn = w & 1;
  const int mtile = blockIdx.x;
  const int ntile = (MODE == 3) ? 0 : (int)blockIdx.y;
  const int ks    = (MODE == 3) ? (int)blockIdx.y : 0;
  const int kb0   = (MODE == 3) ? ks * 1024 : 0;

  int srow[2];
  srow[0] = w * 16 + (l >> 2);
  srow[1] = 64 + srow[0];
  const int chunk = (l & 3) ^ ((srow[0] >> 1) & 3);
  const int scol = chunk * 8;

  const u16* aptr[2];
  const u16* bptr[2];
#pragma unroll
  for (int i = 0; i < 2; ++i) {
    aptr[i] = A + (size_t)(mtile * 128 + srow[i]) * LDA + kb0 + scol;
    bptr[i] = B0 + (size_t)(ntile * 128 + srow[i]) * LDB + kb0 + scol;
  }

  char* ldsc = (char*)lds;
  auto stage = [&](int buf, int kt) {
    const int kk = kt * 32;
    char* base = ldsc + buf * 16384;
#pragma unroll
    for (int i = 0; i < 2; ++i) {
      gload_lds16(aptr[i] + kk, base + i * 4096 + w * 1024);
      gload_lds16(bptr[i] + kk, base + 8192 + i * 4096 + w * 1024);
    }
  };

  f32x4 acc[4][4];
  f32x4 zf = {0.f, 0.f, 0.f, 0.f};
#pragma unroll
  for (int a = 0; a < 4; ++a)
#pragma unroll
    for (int b = 0; b < 4; ++b) acc[a][b] = zf;

  stage(0, 0);
  __syncthreads();

  const int kq   = l >> 4;
  const int arow = wm * 64 + (l & 15);
  const int brow = wn * 64 + (l & 15);
  const int axor = (kq ^ ((arow >> 1) & 3)) << 4;
  const int bxor = (kq ^ ((brow >> 1) & 3)) << 4;

  for (int kt = 0; kt < NKI; ++kt) {
    const int buf = kt & 1;
    if (kt + 1 < NKI) stage(buf ^ 1, kt + 1);
    const char* bA = ldsc + buf * 16384;
    const char* bB = bA + 8192;
    bf16x8 af[4], bfr[4];
#pragma unroll
    for (int fm = 0; fm < 4; ++fm)
      af[fm] = *(const bf16x8*)(bA + (arow + fm * 16) * 64 + axor);
#pragma unroll
    for (int fn = 0; fn < 4; ++fn)
      bfr[fn] = *(const bf16x8*)(bB + (brow + fn * 16) * 64 + bxor);
#pragma unroll
    for (int fm = 0; fm < 4; ++fm)
#pragma unroll
      for (int fn = 0; fn < 4; ++fn)
        acc[fm][fn] = __builtin_amdgcn_mfma_f32_16x16x32_bf16(af[fm], bfr[fn], acc[fm][fn], 0, 0, 0);
    __syncthreads();
  }

  const int lq = l >> 4;
  const int lr = l & 15;

  if (MODE == 0) {
    u16* X = (u16*)Cout;
#pragma unroll
    for (int fm = 0; fm < 4; ++fm)
#pragma unroll
      for (int fn = 0; fn < 4; ++fn)
        for (int j = 0; j < 4; ++j) {
          int m = mtile * 128 + wm * 64 + fm * 16 + lq * 4 + j;
          int c = ntile * 128 + wn * 64 + fn * 16 + lr;
          int e = idx[m];
          u16 v = (((c & 127) >> 4) == e) ? f2bf(SCAL * acc[fm][fn][j]) : (u16)0;
          X[(size_t)m * LDXA + 2048 + c] = v;
        }
  } else {
    float* P = (float*)Cout + (size_t)ks * NTOK * 128;
#pragma unroll
    for (int fm = 0; fm < 4; ++fm)
#pragma unroll
      for (int fn = 0; fn < 4; ++fn)
        for (int j = 0; j < 4; ++j) {
          int m = mtile * 128 + wm * 64 + fm * 16 + lq * 4 + j;
          int c = wn * 64 + fn * 16 + lr;
          P[(size_t)m * 128 + c] = acc[fm][fn][j];
        }
  }
}

// ================= gemm_gu: 256x256, one barrier per K=32 slice, DEPTH-2 prefetch ====
// r9's regression root cause: stage p+3 / vm(4) = depth-1 prefetch -> every phase
// stalls on a load issued ~700cy earlier (HBM ~2000cy under load). Fix: stage slice
// p+4 into slot p&3 with vm(8) = depth-2 (~2200cy tolerance). Ledger: slice s staged
// at s-4 (slot s&3), retired by vm(8) at s-2, barrier, read-ahead at s-1, computed
// at s. In-loop read slot (p+1)&3 != stage slot p&3. Prologue: stage 0..3, vm(8)
// retires 0,1; barrier; pre-read slice 0; EXTRA barrier (separates pre-read of
// slot0 from phase-0's STG into slot0 - same-interval RW hazard).
__global__ __launch_bounds__(512, 2)
void gemm_gu(const u16* __restrict__ Ag,
             const u16* __restrict__ B0g,
             const u16* __restrict__ B1g,
             u16* __restrict__ H)
{
  constexpr int NSL = 72;   // K slices of 32 elems (2304 / 32)
  __shared__ char L[131072];   // A: z*16384 (0..64K), B: 65536 + z*16384

  const int tid = threadIdx.x, w = tid >> 6, l = tid & 63;
  const int wm = w >> 2, wn = w & 3;
  const int bid = blockIdx.x;
  const int rr = bid >> 3;
  const int mtile = rr >> 3;
  const int ntile = (bid & 7) * 8 + (rr & 7);

  const u16 *agb0, *agb1, *bgb0, *bgb1;
  {
    int row0 = tid >> 2, row1 = 128 + row0;
    int lc = (tid & 3) ^ ((row0 >> 1) & 3);   // same for row0+128
    agb0 = Ag + (size_t)(mtile * 256 + row0) * LDXA + lc * 8;
    agb1 = Ag + (size_t)(mtile * 256 + row1) * LDXA + lc * 8;
    int c0 = ntile * 128 + ((row0 >> 5) << 4) + (row0 & 15);
    int c1 = ntile * 128 + ((row1 >> 5) << 4) + (row1 & 15);
    bgb0 = (((row0 >> 4) & 1) ? B1g : B0g) + (size_t)c0 * LDXA + lc * 8;
    bgb1 = (((row1 >> 4) & 1) ? B1g : B0g) + (size_t)c1 * LDXA + lc * 8;
  }
  const int sdst = w * 1024;

// stage full slice s into slot z (A 2 gloads + B 2 gloads)
#define STG(z, s) { const int ko_ = ((s) < NSL ? (s) : NSL - 1) * 32; \
    gload_lds16(agb0 + ko_, L + (z) * 16384 + sdst); \
    gload_lds16(agb1 + ko_, L + (z) * 16384 + 8192 + sdst); \
    gload_lds16(bgb0 + ko_, L + 65536 + (z) * 16384 + sdst); \
    gload_lds16(bgb1 + ko_, L + 65536 + (z) * 16384 + 8192 + sdst); }

  const int lr = l & 15;
  const int kob = (((l >> 4) ^ ((lr >> 1) & 3)) << 4);
  const int abase = (wm * 128 + lr) * 64 + kob;
  const int bbase = (wn * 64 + lr) * 64 + kob;

  bf16x8 A0_[8], A1_[8], B0_[4], B1_[4];
#define RDA8(S, z) _Pragma("unroll") for (int f = 0; f < 8; ++f) \
    S[f] = *(const bf16x8*)(L + (z) * 16384 + abase + (f >> 2) * 4096 + (f & 3) * 1024);
#define RDB(S, z) _Pragma("unroll") for (int f = 0; f < 4; ++f) \
    S[f] = *(const bf16x8*)(L + 65536 + (z) * 16384 + bbase + f * 1024);

  f32x4 acc[8][4];
  f32x4 zf = {0.f, 0.f, 0.f, 0.f};
#pragma unroll
  for (int a = 0; a < 8; ++a)
#pragma unroll
    for (int b = 0; b < 4; ++b) acc[a][b] = zf;

#define MF32(AS, BS) \
  __builtin_amdgcn_s_setprio(1); \
  _Pragma("unroll") for (int f = 0; f < 8; ++f) \
    _Pragma("unroll") for (int n = 0; n < 4; ++n) \
      acc[f][n] = __builtin_amdgcn_mfma_f32_16x16x32_bf16(AS[f], BS[n], acc[f][n], 0, 0, 0); \
  __builtin_amdgcn_s_setprio(0);

#define VMW  { asm volatile("s_waitcnt vmcnt(8)" ::: "memory"); __builtin_amdgcn_sched_barrier(0); }
#define PEND { __builtin_amdgcn_sched_barrier(0); __builtin_amdgcn_s_barrier(); __builtin_amdgcn_sched_barrier(0); }

  // prologue: stage slices 0..3 into slots 0..3 (16 loads); vm(8) retires 0,1;
  // BARRIER; pre-read slice 0; EXTRA BARRIER (slot0 RW separation from phase 0).
  STG(0, 0) STG(1, 1) STG(2, 2) STG(3, 3)
  VMW
  PEND
  RDB(B0_, 0) RDA8(A0_, 0)
  PEND

  for (int it = 0; it < NSL / 4; ++it) {
    const int s = 4 * it;
    // phase s+0: compute slice s (set0); read s+1 (slot1) -> set1; stage s+4 -> slot0
    STG(0, s + 4)
    RDB(B1_, 1) RDA8(A1_, 1)
    MF32(A0_, B0_)  VMW  PEND
    // phase s+1: compute s+1 (set1); read s+2 (slot2) -> set0; stage s+5 -> slot1
    STG(1, s + 5)
    RDB(B0_, 2) RDA8(A0_, 2)
    MF32(A1_, B1_)  VMW  PEND
    // phase s+2: compute s+2 (set0); read s+3 (slot3) -> set1; stage s+6 -> slot2
    STG(2, s + 6)
    RDB(B1_, 3) RDA8(A1_, 3)
    MF32(A0_, B0_)  VMW  PEND
    // phase s+3: compute s+3 (set1); read s+4 (slot0) -> set0; stage s+7 -> slot3
    STG(3, s + 7)
    RDB(B0_, 0) RDA8(A0_, 0)
    MF32(A1_, B1_)  VMW  PEND
  }

  const int lq = l >> 4;
#pragma unroll
  for (int fm = 0; fm < 8; ++fm)
    for (int jj = 0; jj < 4; ++jj) {
      const int m = mtile * 256 + wm * 128 + fm * 16 + lq * 4 + jj;
#pragma unroll
      for (int p = 0; p < 2; ++p) {
        float g = acc[fm][2 * p][jj];
        float u = acc[fm][2 * p + 1][jj];
        float e = __builtin_amdgcn_exp2f(g * -1.44269504089f);
        float h = g * __builtin_amdgcn_rcpf(1.f + e) * u;
        const int c = ntile * 128 + (wn * 2 + p) * 16 + lr;
        H[(size_t)m * LDHA + c] = f2bf(h);
      }
    }
#undef RDA8
#undef RDB
#undef MF32
#undef STG
#undef VMW
#undef PEND
}

// ================= gemm6: down-proj 128x256, ring-of-6 slots, read-ahead =========
// (unchanged from r8 — 3-phase vm depth, near its LDS-pipe floor)
__global__ __launch_bounds__(512, 2)
void gemm6(const u16* __restrict__ Ag,
           const u16* __restrict__ Bg,
           float* __restrict__ C)
{
  __shared__ char L[147456];
  const int tid = threadIdx.x, w = tid >> 6, l = tid & 63;
  const int wm = w >> 2, wn = w & 3;   // wave tile 64m x 64n
  const int bid = blockIdx.x;
  const int swz = (bid & 7) * 32 + (bid >> 3);
  const int mtile = swz >> 3;
  const int ntile = swz & 7;

  const u16 *agb0, *bgb0, *bgb1;
  {
    int row0 = tid >> 2;
    int lc = (tid & 3) ^ ((row0 >> 1) & 3);
    agb0 = Ag + (size_t)(mtile * 128 + row0) * LDHA + lc * 8;
    bgb0 = Bg + (size_t)(ntile * 256 + row0) * LDHA + lc * 8;
    bgb1 = Bg + (size_t)(ntile * 256 + 128 + row0) * LDHA + lc * 8;
  }
  const int sdst = w * 1024;

#define STG6(z, g) { const int gg_ = (g) < 260 ? (g) : 259; \
    const int ko_ = (gg_ >> 1) * 64 + (gg_ & 1) * 32; \
    gload_lds16(agb0 + ko_, L + (z) * 24576 + sdst); \
    gload_lds16(bgb0 + ko_, L + (z) * 24576 + 8192 + sdst); \
    gload_lds16(bgb1 + ko_, L + (z) * 24576 + 16384 + sdst); }

  const int lr = l & 15;
  const int kob = (((l >> 4) ^ ((lr >> 1) & 3)) << 4);
  const int abase = (wm * 64 + lr) * 64 + kob;
  const int bbase = (wn * 64 + lr) * 64 + kob;

  bf16x8 A0_[4], A1_[4], B0_[4], B1_[4];
#define RDA6(S, z) _Pragma("unroll") for (int f = 0; f < 4; ++f) \
    S[f] = *(const bf16x8*)(L + (z) * 24576 + abase + f * 1024);
#define RDB6(S, z) _Pragma("unroll") for (int f = 0; f < 4; ++f) \
    S[f] = *(const bf16x8*)(L + (z) * 24576 + 8192 + bbase + f * 1024);

  f32x4 acc[4][4];
  f32x4 zf = {0.f, 0.f, 0.f, 0.f};
#pragma unroll
  for (int a = 0; a < 4; ++a)
#pragma unroll
    for (int b = 0; b < 4; ++b) acc[a][b] = zf;

#define MF6(AS, BS) \
  __builtin_amdgcn_s_setprio(1); \
  _Pragma("unroll") for (int f = 0; f < 4; ++f) \
    _Pragma("unroll") for (int n = 0; n < 4; ++n) \
      acc[f][n] = __builtin_amdgcn_mfma_f32_16x16x32_bf16(AS[f], BS[n], acc[f][n], 0, 0, 0); \
  __builtin_amdgcn_s_setprio(0);

#define VMW6 { asm volatile("s_waitcnt vmcnt(6)" ::: "memory"); __builtin_amdgcn_sched_barrier(0); }
#define PEND6 { __builtin_amdgcn_sched_barrier(0); __builtin_amdgcn_s_barrier(); __builtin_amdgcn_sched_barrier(0); }

  STG6(0, 0) STG6(1, 1) STG6(2, 2) STG6(3, 3)
  VMW6
  PEND6
  RDB6(B0_, 0) RDA6(A0_, 0)

  for (int it = 0; it < 43; ++it) {
    const int g4 = it * 6 + 4;
    STG6(4, g4)      RDB6(B1_, 1) RDA6(A1_, 1)  MF6(A0_, B0_)  VMW6  PEND6
    STG6(5, g4 + 1)  RDB6(B0_, 2) RDA6(A0_, 2)  MF6(A1_, B1_)  VMW6  PEND6
    STG6(0, g4 + 2)  RDB6(B1_, 3) RDA6(A1_, 3)  MF6(A0_, B0_)  VMW6  PEND6
    STG6(1, g4 + 3)  RDB6(B0_, 4) RDA6(A0_, 4)  MF6(A1_, B1_)  VMW6  PEND6
    STG6(2, g4 + 4)  RDB6(B1_, 5) RDA6(A1_, 5)  MF6(A0_, B0_)  VMW6  PEND6
    STG6(3, g4 + 5)  RDB6(B0_, 0) RDA6(A0_, 0)  MF6(A1_, B1_)  VMW6  PEND6
  }
  RDB6(B1_, 1) RDA6(A1_, 1)
  MF6(A0_, B0_)
  MF6(A1_, B1_)

  const int lq = l >> 4;
#pragma unroll
  for (int fm = 0; fm < 4; ++fm)
#pragma unroll
    for (int n = 0; n < 4; ++n)
      for (int jj = 0; jj < 4; ++jj) {
        const int m = mtile * 128 + wm * 64 + fm * 16 + lq * 4 + jj;
        const int c = ntile * 256 + wn * 64 + n * 16 + lr;
        C[(size_t)m * DM + c] = acc[fm][n][jj];
      }
#undef RDA6
#undef RDB6
#undef MF6
#undef STG6
#undef VMW6
#undef PEND6
}

// ---------------- t_down split-K reduce -> masked SCAL*td into ha ext cols ----------------
__global__ void td_reduce(const float* __restrict__ part,
                          const int* __restrict__ idx,
                          u16* __restrict__ ha) {
  int i = blockIdx.x * blockDim.x + threadIdx.x;
  int m = i >> 7, c = i & 127;
  float s = 0.f;
#pragma unroll
  for (int k = 0; k < 8; ++k) s += part[(size_t)k * NTOK * 128 + i];
  u16 v = ((c >> 4) == idx[m]) ? f2bf(SCAL * s) : (u16)0;
  ha[(size_t)m * LDHA + 8192 + c] = v;
}

extern "C" void kernel_launch(void* const* d_in, const int* in_sizes, int n_in,
                              void* d_out, int out_size, void* d_ws, size_t ws_size,
                              hipStream_t stream) {
  const float* x  = (const float*)d_in[0];
  const float* wg = (const float*)d_in[1];
  const float* wu = (const float*)d_in[2];
  const float* wd = (const float*)d_in[3];
  const float* rw = (const float*)d_in[4];
  const float* rb = (const float*)d_in[5];
  const float* Ag = (const float*)d_in[6];
  const float* Bg = (const float*)d_in[7];
  const float* Au = (const float*)d_in[8];
  const float* Bu = (const float*)d_in[9];
  const float* Ad = (const float*)d_in[10];
  const float* Bd = (const float*)d_in[11];

  float* out      = (float*)d_out;
  float* out_rout = out + (size_t)NTOK * DM;
  float* out_ec   = out_rout + (size_t)NTOK * NEXP;

  char* ws = (char*)d_ws;
  size_t off = 0;
  auto take = [&](size_t b) { void* p = ws + off; off += (b + 255) & ~(size_t)255; return p; };
  u16*   xa   = (u16*)take((size_t)NTOK * LDXA * 2);
  u16*   ha   = (u16*)take((size_t)NTOK * LDHA * 2);
  u16*   wgx  = (u16*)take((size_t)DMLP * LDXA * 2);
  u16*   wux  = (u16*)take((size_t)DMLP * LDXA * 2);
  u16*   wdx  = (u16*)take((size_t)DM * LDHA * 2);
  u16*   Aab  = (u16*)take((size_t)256 * DM * 2);
  u16*   Adb  = (u16*)take((size_t)128 * DMLP * 2);
  float* tdp  = (float*)take((size_t)8 * NTOK * 128 * 4);
  int*   idx  = (int*)take((size_t)NTOK * 4);
  if (off > ws_size) return;

  prep_kernel<<<2048, 256, 0, stream>>>(wg, wu, wd, Ag, Au, Ad, Bg, Bu, Bd,
                                        wgx, wux, wdx, Aab, Adb);

  router_kernel<<<NTOK / 4, 256, 0, stream>>>(x, rw, rb, xa, idx, out_rout, out_ec);

  // t = xa @ [A_gate;A_up]^T -> masked SCAL*t into xa[:, 2048:2304]
  gemm_kernel<0><<<dim3(32, 2), 256, 0, stream>>>(xa, Aab, idx, xa);
  // gate/up fused (lora in K) + silu*mul -> ha[:, 0:8192]
  gemm_gu<<<1024, 512, 0, stream>>>(xa, wgx, wux, ha);
  // t_down partials: ha[:, :8192] @ A_down^T, 8-way K-split
  gemm_kernel<3><<<dim3(32, 8), 256, 0, stream>>>(ha, Adb, idx, tdp);
  td_reduce<<<NTOK * 128 / 256, 256, 0, stream>>>(tdp, idx, ha);
  // down (lora in K) -> f32 out
  gemm6<<<256, 512, 0, stream>>>(ha, wdx, out);
}

// Round 11
// 564.000 us; speedup vs baseline: 1.0939x; 1.0939x over previous
//
#include <hip/hip_runtime.h>
#include <stdint.h>

#define NTOK   4096
#define DM     2048
#define DMLP   8192
#define NEXP   8
#define NRANK  16
#define SCAL   2.0f

// Wide-A strides (LoRA folded into K):
//   xa: [4096, 2304]  = [x_bf16 | SCAL*t_gate_masked(128) | SCAL*t_up_masked(128)]
//   ha: [4096, 8320]  = [h_bf16 | SCAL*t_down_masked(128)]
#define LDXA 2304
#define LDHA 8320

typedef __bf16 bf16x8 __attribute__((ext_vector_type(8)));
typedef float  f32x4  __attribute__((ext_vector_type(4)));
typedef unsigned short u16;

__device__ __forceinline__ u16 f2bf(float f) {
  unsigned u = __float_as_uint(f);
  u += 0x7fffu + ((u >> 16) & 1u);   // RNE
  return (u16)(u >> 16);
}

__device__ __forceinline__ void gload_lds16(const void* g, void* l) {
  __builtin_amdgcn_global_load_lds((const __attribute__((address_space(1))) void*)g,
                                   (__attribute__((address_space(3))) void*)l, 16, 0, 0);
}

// ------- fused prep + router: converts, extended weights, routing, x->bf16 -------
// Router part (blocks 0..1023, 4 rows each) and weight-prep part (all 2048 blocks,
// grid-stride) touch disjoint buffers; fusing removes one launch and overlaps the
// HBM streams.
__global__ void prep_kernel(const float* __restrict__ wg, const float* __restrict__ wu,
                            const float* __restrict__ wd,
                            const float* __restrict__ Ag, const float* __restrict__ Au,
                            const float* __restrict__ Ad,
                            const float* __restrict__ Bg, const float* __restrict__ Bu,
                            const float* __restrict__ Bd,
                            u16* __restrict__ wgx, u16* __restrict__ wux,
                            u16* __restrict__ wdx, u16* __restrict__ Aab,
                            u16* __restrict__ Adb,
                            const float* __restrict__ x,
                            const float* __restrict__ rw,
                            const float* __restrict__ rb,
                            u16* __restrict__ xa,
                            int* __restrict__ idx,
                            float* __restrict__ out_rout,
                            float* __restrict__ out_ec) {
  // ---- router part ----
  if (blockIdx.x < NTOK / 4) {
    const int wave = threadIdx.x >> 6;
    const int lane = threadIdx.x & 63;
    const int m = blockIdx.x * 4 + wave;

    const float4* xrow = (const float4*)(x + (size_t)m * DM + lane * 32);
    float4 xv[8];
#pragma unroll
    for (int i = 0; i < 8; ++i) xv[i] = xrow[i];

    uint4 o[4];
    unsigned* op = (unsigned*)o;
#pragma unroll
    for (int i = 0; i < 8; ++i) {
      op[2*i]   = (unsigned)f2bf(xv[i].x) | ((unsigned)f2bf(xv[i].y) << 16);
      op[2*i+1] = (unsigned)f2bf(xv[i].z) | ((unsigned)f2bf(xv[i].w) << 16);
    }
    uint4* xdst = (uint4*)(xa + (size_t)m * LDXA + lane * 32);
#pragma unroll
    for (int i = 0; i < 4; ++i) xdst[i] = o[i];

    float lg[NEXP];
#pragma unroll
    for (int e = 0; e < NEXP; ++e) {
      const float4* wrow = (const float4*)(rw + (size_t)e * DM + lane * 32);
      float s = 0.f;
#pragma unroll
      for (int i = 0; i < 8; ++i) {
        float4 wv = wrow[i];
        s += xv[i].x*wv.x + xv[i].y*wv.y + xv[i].z*wv.z + xv[i].w*wv.w;
      }
#pragma unroll
      for (int off = 32; off > 0; off >>= 1) s += __shfl_xor(s, off, 64);
      lg[e] = s + rb[e];
    }

    float mx = lg[0];
#pragma unroll
    for (int e = 1; e < NEXP; ++e) mx = fmaxf(mx, lg[e]);
    float ex[NEXP], se = 0.f;
#pragma unroll
    for (int e = 0; e < NEXP; ++e) { ex[e] = expf(lg[e] - mx); se += ex[e]; }
    float inv = 1.f / se;
    int best = 0; float bv = lg[0];
#pragma unroll
    for (int e = 1; e < NEXP; ++e) if (lg[e] > bv) { bv = lg[e]; best = e; }

    if (lane == 0) {
      idx[m] = best;
#pragma unroll
      for (int e = 0; e < NEXP; ++e) {
        float r = ex[e] * inv;
        out_rout[(size_t)m * NEXP + e] = r;
        float hard = (e == best) ? 1.f : 0.f;
        out_ec[(size_t)m * NEXP + e] = (hard - r) + r;
      }
    }
  }

  // ---- weight prep part (grid-stride over all blocks) ----
  const int gt = blockIdx.x * blockDim.x + threadIdx.x;
  const int gs = gridDim.x * blockDim.x;

  for (int i = gt; i < DMLP * 512; i += gs) {
    const int o = i >> 9, c = (i & 511) << 2;
    float4 v = ((const float4*)wg)[i];
    ushort4 ov; ov.x = f2bf(v.x); ov.y = f2bf(v.y); ov.z = f2bf(v.z); ov.w = f2bf(v.w);
    *(ushort4*)(wgx + (size_t)o * LDXA + c) = ov;
    v = ((const float4*)wu)[i];
    ov.x = f2bf(v.x); ov.y = f2bf(v.y); ov.z = f2bf(v.z); ov.w = f2bf(v.w);
    *(ushort4*)(wux + (size_t)o * LDXA + c) = ov;
  }
  for (int i = gt; i < DM * 2048; i += gs) {
    const int o = i >> 11, c = (i & 2047) << 2;
    float4 v = ((const float4*)wd)[i];
    ushort4 ov; ov.x = f2bf(v.x); ov.y = f2bf(v.y); ov.z = f2bf(v.z); ov.w = f2bf(v.w);
    *(ushort4*)(wdx + (size_t)o * LDHA + c) = ov;
  }
  for (int i = gt; i < 256 * 512; i += gs) {
    float4 v = (i < 128 * 512) ? ((const float4*)Ag)[i] : ((const float4*)Au)[i - 128 * 512];
    ushort4 ov; ov.x = f2bf(v.x); ov.y = f2bf(v.y); ov.z = f2bf(v.z); ov.w = f2bf(v.w);
    ((ushort4*)Aab)[i] = ov;
  }
  for (int i = gt; i < 128 * 2048; i += gs) {
    float4 v = ((const float4*)Ad)[i];
    ushort4 ov; ov.x = f2bf(v.x); ov.y = f2bf(v.y); ov.z = f2bf(v.z); ov.w = f2bf(v.w);
    ((ushort4*)Adb)[i] = ov;
  }
  for (int i = gt; i < DMLP * 256; i += gs) {
    const int o = i >> 8, c = i & 255;
    const int e = (c & 127) >> 4, r = c & 15;
    u16 vg = 0, vu = 0;
    if (c < 128) vg = f2bf(Bg[((size_t)e * DMLP + o) * NRANK + r]);
    else         vu = f2bf(Bu[((size_t)e * DMLP + o) * NRANK + r]);
    wgx[(size_t)o * LDXA + 2048 + c] = vg;
    wux[(size_t)o * LDXA + 2048 + c] = vu;
  }
  for (int i = gt; i < DM * 128; i += gs) {
    const int o = i >> 7, c = i & 127;
    const int e = c >> 4, r = c & 15;
    wdx[(size_t)o * LDHA + 8192 + c] = f2bf(Bd[((size_t)e * DM + o) * NRANK + r]);
  }
}

// ---------------- old 128x128 GEMM core (small MODE 0 / MODE 3) ----------------
template<int MODE>
__global__ __launch_bounds__(256, 2)
void gemm_kernel(const u16* __restrict__ A,
                 const u16* __restrict__ B0,
                 const int* __restrict__ idx,
                 void* __restrict__ Cout)
{
  constexpr int LDA = (MODE == 0) ? LDXA : LDHA;
  constexpr int LDB = (MODE == 0) ? 2048 : 8192;
  constexpr int NKI = (MODE == 0) ? 64 : 32;

  __shared__ u16 lds[16384];

  const int tid = threadIdx.x;
  const int w = tid >> 6;
  const int l = tid & 63;
  const int wm = w >> 1, wn = w & 1;
  const int mtile = blockIdx.x;
  const int ntile = (MODE == 3) ? 0 : (int)blockIdx.y;
  const int ks    = (MODE == 3) ? (int)blockIdx.y : 0;
  const int kb0   = (MODE == 3) ? ks * 1024 : 0;

  int srow[2];
  srow[0] = w * 16 + (l >> 2);
  srow[1] = 64 + srow[0];
  const int chunk = (l & 3) ^ ((srow[0] >> 1) & 3);
  const int scol = chunk * 8;

  const u16* aptr[2];
  const u16* bptr[2];
#pragma unroll
  for (int i = 0; i < 2; ++i) {
    aptr[i] = A + (size_t)(mtile * 128 + srow[i]) * LDA + kb0 + scol;
    bptr[i] = B0 + (size_t)(ntile * 128 + srow[i]) * LDB + kb0 + scol;
  }

  char* ldsc = (char*)lds;
  auto stage = [&](int buf, int kt) {
    const int kk = kt * 32;
    char* base = ldsc + buf * 16384;
#pragma unroll
    for (int i = 0; i < 2; ++i) {
      gload_lds16(aptr[i] + kk, base + i * 4096 + w * 1024);
      gload_lds16(bptr[i] + kk, base + 8192 + i * 4096 + w * 1024);
    }
  };

  f32x4 acc[4][4];
  f32x4 zf = {0.f, 0.f, 0.f, 0.f};
#pragma unroll
  for (int a = 0; a < 4; ++a)
#pragma unroll
    for (int b = 0; b < 4; ++b) acc[a][b] = zf;

  stage(0, 0);
  __syncthreads();

  const int kq   = l >> 4;
  const int arow = wm * 64 + (l & 15);
  const int brow = wn * 64 + (l & 15);
  const int axor = (kq ^ ((arow >> 1) & 3)) << 4;
  const int bxor = (kq ^ ((brow >> 1) & 3)) << 4;

  for (int kt = 0; kt < NKI; ++kt) {
    const int buf = kt & 1;
    if (kt + 1 < NKI) stage(buf ^ 1, kt + 1);
    const char* bA = ldsc + buf * 16384;
    const char* bB = bA + 8192;
    bf16x8 af[4], bfr[4];
#pragma unroll
    for (int fm = 0; fm < 4; ++fm)
      af[fm] = *(const bf16x8*)(bA + (arow + fm * 16) * 64 + axor);
#pragma unroll
    for (int fn = 0; fn < 4; ++fn)
      bfr[fn] = *(const bf16x8*)(bB + (brow + fn * 16) * 64 + bxor);
#pragma unroll
    for (int fm = 0; fm < 4; ++fm)
#pragma unroll
      for (int fn = 0; fn < 4; ++fn)
        acc[fm][fn] = __builtin_amdgcn_mfma_f32_16x16x32_bf16(af[fm], bfr[fn], acc[fm][fn], 0, 0, 0);
    __syncthreads();
  }

  const int lq = l >> 4;
  const int lr = l & 15;

  if (MODE == 0) {
    u16* X = (u16*)Cout;
#pragma unroll
    for (int fm = 0; fm < 4; ++fm)
#pragma unroll
      for (int fn = 0; fn < 4; ++fn)
        for (int j = 0; j < 4; ++j) {
          int m = mtile * 128 + wm * 64 + fm * 16 + lq * 4 + j;
          int c = ntile * 128 + wn * 64 + fn * 16 + lr;
          int e = idx[m];
          u16 v = (((c & 127) >> 4) == e) ? f2bf(SCAL * acc[fm][fn][j]) : (u16)0;
          X[(size_t)m * LDXA + 2048 + c] = v;
        }
  } else {
    float* P = (float*)Cout + (size_t)ks * NTOK * 128;
#pragma unroll
    for (int fm = 0; fm < 4; ++fm)
#pragma unroll
      for (int fn = 0; fn < 4; ++fn)
        for (int j = 0; j < 4; ++j) {
          int m = mtile * 128 + wm * 64 + fm * 16 + lq * 4 + j;
          int c = wn * 64 + fn * 16 + lr;
          P[(size_t)m * 128 + c] = acc[fm][fn][j];
        }
  }
}

// ================= gemm_gu: 256x256 8-phase, register read-ahead (r8 proven) =====
// Slots z0..z3. Per phase: stage one half-slot, read NEXT phase's fragments into
// the alternate named reg set, MFMA current set, THEN vm(6) at even phases.
// Cross-wave rule: slot read only after a barrier following every wave's covering
// vmcnt; prologue pre-read sits after the barrier. This is the proven 260 us
// schedule (r8); r9/r10 merged-phase variants both regressed — do not merge phases.
__global__ __launch_bounds__(512, 2)
void gemm_gu(const u16* __restrict__ Ag,
             const u16* __restrict__ B0g,
             const u16* __restrict__ B1g,
             u16* __restrict__ H)
{
  constexpr int NKT = 36;
  __shared__ char L[131072];   // A: z*16384 (0..64K), B: 65536 + z*16384

  const int tid = threadIdx.x, w = tid >> 6, l = tid & 63;
  const int wm = w >> 2, wn = w & 3;
  const int bid = blockIdx.x;
  const int rr = bid >> 3;
  const int mtile = rr >> 3;
  const int ntile = (bid & 7) * 8 + (rr & 7);

  const u16 *agb0, *agb1, *bgb0, *bgb1;
  {
    int row0 = tid >> 2, row1 = 128 + row0;
    int lc = (tid & 3) ^ ((row0 >> 1) & 3);   // same for row0+128
    agb0 = Ag + (size_t)(mtile * 256 + row0) * LDXA + lc * 8;
    agb1 = Ag + (size_t)(mtile * 256 + row1) * LDXA + lc * 8;
    int c0 = ntile * 128 + ((row0 >> 5) << 4) + (row0 & 15);
    int c1 = ntile * 128 + ((row1 >> 5) << 4) + (row1 & 15);
    bgb0 = (((row0 >> 4) & 1) ? B1g : B0g) + (size_t)c0 * LDXA + lc * 8;
    bgb1 = (((row1 >> 4) & 1) ? B1g : B0g) + (size_t)c1 * LDXA + lc * 8;
  }
  const int sdst = w * 1024;

#define STGA(z, kt) { const int ko_ = ((kt) < NKT ? (kt) : NKT - 1) * 64 + ((z) & 1) * 32; \
    gload_lds16(agb0 + ko_, L + (z) * 16384 + sdst); \
    gload_lds16(agb1 + ko_, L + (z) * 16384 + 8192 + sdst); }
#define STGB(z, kt) { const int ko_ = ((kt) < NKT ? (kt) : NKT - 1) * 64 + ((z) & 1) * 32; \
    gload_lds16(bgb0 + ko_, L + 65536 + (z) * 16384 + sdst); \
    gload_lds16(bgb1 + ko_, L + 65536 + (z) * 16384 + 8192 + sdst); }

  const int lr = l & 15;
  const int kob = (((l >> 4) ^ ((lr >> 1) & 3)) << 4);
  const int abase = (wm * 128 + lr) * 64 + kob;
  const int bbase = (wn * 64 + lr) * 64 + kob;

  bf16x8 A0_[4], A1_[4], B0_[4], B1_[4];
#define RDA(S, z, qa) _Pragma("unroll") for (int f = 0; f < 4; ++f) \
    S[f] = *(const bf16x8*)(L + (z) * 16384 + abase + (qa) * 4096 + f * 1024);
#define RDB(S, z) _Pragma("unroll") for (int f = 0; f < 4; ++f) \
    S[f] = *(const bf16x8*)(L + 65536 + (z) * 16384 + bbase + f * 1024);

  f32x4 acc[8][4];
  f32x4 zf = {0.f, 0.f, 0.f, 0.f};
#pragma unroll
  for (int a = 0; a < 8; ++a)
#pragma unroll
    for (int b = 0; b < 4; ++b) acc[a][b] = zf;

#define MF(qa, AS, BS) \
  __builtin_amdgcn_s_setprio(1); \
  _Pragma("unroll") for (int f = 0; f < 4; ++f) \
    _Pragma("unroll") for (int n = 0; n < 4; ++n) \
      acc[(qa) * 4 + f][n] = __builtin_amdgcn_mfma_f32_16x16x32_bf16(AS[f], BS[n], acc[(qa) * 4 + f][n], 0, 0, 0); \
  __builtin_amdgcn_s_setprio(0);

#define VMW  { asm volatile("s_waitcnt vmcnt(6)" ::: "memory"); __builtin_amdgcn_sched_barrier(0); }
#define PEND { __builtin_amdgcn_sched_barrier(0); __builtin_amdgcn_s_barrier(); __builtin_amdgcn_sched_barrier(0); }

  // prologue: stage z0<-kt0s0, z1<-kt0s1, z2<-kt1s0 (FIFO order); vm(6); BARRIER
  // (z0 globally valid); then pre-read z0.
  STGA(0, 0) STGB(0, 0)
  STGA(1, 0) STGB(1, 0)
  STGA(2, 1) STGB(2, 1)
  VMW
  PEND
  RDB(B0_, 0) RDA(A0_, 0, 0)

  for (int it = 0; it < NKT / 2; ++it) {
    const int k1 = 2 * it + 1, k2 = 2 * it + 2, k3 = 2 * it + 3;
    // P0: compute z0.qa0
    STGA(3, k1)
    RDA(A1_, 0, 1)
    MF(0, A0_, B0_)  VMW  PEND
    // P1: compute z0.qa1
    STGB(3, k1)
    RDB(B1_, 1) RDA(A0_, 1, 0)
    MF(1, A1_, B0_)  PEND
    // P2: compute z1.qa0
    STGA(0, k2)
    RDA(A1_, 1, 1)
    MF(0, A0_, B1_)  VMW  PEND
    // P3: compute z1.qa1
    STGB(0, k2)
    RDB(B0_, 2) RDA(A0_, 2, 0)
    MF(1, A1_, B1_)  PEND
    // P4: compute z2.qa0
    STGA(1, k2)
    RDA(A1_, 2, 1)
    MF(0, A0_, B0_)  VMW  PEND
    // P5: compute z2.qa1
    STGB(1, k2)
    RDB(B1_, 3) RDA(A0_, 3, 0)
    MF(1, A1_, B0_)  PEND
    // P6: compute z3.qa0
    STGA(2, k3)
    RDA(A1_, 3, 1)
    MF(0, A0_, B1_)  VMW  PEND
    // P7: compute z3.qa1
    STGB(2, k3)
    RDB(B0_, 0) RDA(A0_, 0, 0)
    MF(1, A1_, B1_)  PEND
  }

  const int lq = l >> 4;
#pragma unroll
  for (int fm = 0; fm < 8; ++fm)
    for (int jj = 0; jj < 4; ++jj) {
      const int m = mtile * 256 + wm * 128 + fm * 16 + lq * 4 + jj;
#pragma unroll
      for (int p = 0; p < 2; ++p) {
        float g = acc[fm][2 * p][jj];
        float u = acc[fm][2 * p + 1][jj];
        float e = __builtin_amdgcn_exp2f(g * -1.44269504089f);
        float h = g * __builtin_amdgcn_rcpf(1.f + e) * u;
        const int c = ntile * 128 + (wn * 2 + p) * 16 + lr;
        H[(size_t)m * LDHA + c] = f2bf(h);
      }
    }
#undef RDA
#undef RDB
#undef MF
#undef STGA
#undef STGB
#undef VMW
#undef PEND
}

// ================= gemm6: down-proj 128x256, ring-of-6 slots, read-ahead =========
// (r8 proven version — 3-phase vm depth, VMW post-MFMA)
__global__ __launch_bounds__(512, 2)
void gemm6(const u16* __restrict__ Ag,
           const u16* __restrict__ Bg,
           float* __restrict__ C)
{
  __shared__ char L[147456];
  const int tid = threadIdx.x, w = tid >> 6, l = tid & 63;
  const int wm = w >> 2, wn = w & 3;   // wave tile 64m x 64n
  const int bid = blockIdx.x;
  const int swz = (bid & 7) * 32 + (bid >> 3);
  const int mtile = swz >> 3;
  const int ntile = swz & 7;

  const u16 *agb0, *bgb0, *bgb1;
  {
    int row0 = tid >> 2;
    int lc = (tid & 3) ^ ((row0 >> 1) & 3);
    agb0 = Ag + (size_t)(mtile * 128 + row0) * LDHA + lc * 8;
    bgb0 = Bg + (size_t)(ntile * 256 + row0) * LDHA + lc * 8;
    bgb1 = Bg + (size_t)(ntile * 256 + 128 + row0) * LDHA + lc * 8;
  }
  const int sdst = w * 1024;

#define STG6(z, g) { const int gg_ = (g) < 260 ? (g) : 259; \
    const int ko_ = (gg_ >> 1) * 64 + (gg_ & 1) * 32; \
    gload_lds16(agb0 + ko_, L + (z) * 24576 + sdst); \
    gload_lds16(bgb0 + ko_, L + (z) * 24576 + 8192 + sdst); \
    gload_lds16(bgb1 + ko_, L + (z) * 24576 + 16384 + sdst); }

  const int lr = l & 15;
  const int kob = (((l >> 4) ^ ((lr >> 1) & 3)) << 4);
  const int abase = (wm * 64 + lr) * 64 + kob;
  const int bbase = (wn * 64 + lr) * 64 + kob;

  bf16x8 A0_[4], A1_[4], B0_[4], B1_[4];
#define RDA6(S, z) _Pragma("unroll") for (int f = 0; f < 4; ++f) \
    S[f] = *(const bf16x8*)(L + (z) * 24576 + abase + f * 1024);
#define RDB6(S, z) _Pragma("unroll") for (int f = 0; f < 4; ++f) \
    S[f] = *(const bf16x8*)(L + (z) * 24576 + 8192 + bbase + f * 1024);

  f32x4 acc[4][4];
  f32x4 zf = {0.f, 0.f, 0.f, 0.f};
#pragma unroll
  for (int a = 0; a < 4; ++a)
#pragma unroll
    for (int b = 0; b < 4; ++b) acc[a][b] = zf;

#define MF6(AS, BS) \
  __builtin_amdgcn_s_setprio(1); \
  _Pragma("unroll") for (int f = 0; f < 4; ++f) \
    _Pragma("unroll") for (int n = 0; n < 4; ++n) \
      acc[f][n] = __builtin_amdgcn_mfma_f32_16x16x32_bf16(AS[f], BS[n], acc[f][n], 0, 0, 0); \
  __builtin_amdgcn_s_setprio(0);

#define VMW6 { asm volatile("s_waitcnt vmcnt(6)" ::: "memory"); __builtin_amdgcn_sched_barrier(0); }
#define PEND6 { __builtin_amdgcn_sched_barrier(0); __builtin_amdgcn_s_barrier(); __builtin_amdgcn_sched_barrier(0); }

  STG6(0, 0) STG6(1, 1) STG6(2, 2) STG6(3, 3)
  VMW6
  PEND6
  RDB6(B0_, 0) RDA6(A0_, 0)

  for (int it = 0; it < 43; ++it) {
    const int g4 = it * 6 + 4;
    STG6(4, g4)      RDB6(B1_, 1) RDA6(A1_, 1)  MF6(A0_, B0_)  VMW6  PEND6
    STG6(5, g4 + 1)  RDB6(B0_, 2) RDA6(A0_, 2)  MF6(A1_, B1_)  VMW6  PEND6
    STG6(0, g4 + 2)  RDB6(B1_, 3) RDA6(A1_, 3)  MF6(A0_, B0_)  VMW6  PEND6
    STG6(1, g4 + 3)  RDB6(B0_, 4) RDA6(A0_, 4)  MF6(A1_, B1_)  VMW6  PEND6
    STG6(2, g4 + 4)  RDB6(B1_, 5) RDA6(A1_, 5)  MF6(A0_, B0_)  VMW6  PEND6
    STG6(3, g4 + 5)  RDB6(B0_, 0) RDA6(A0_, 0)  MF6(A1_, B1_)  VMW6  PEND6
  }
  RDB6(B1_, 1) RDA6(A1_, 1)
  MF6(A0_, B0_)
  MF6(A1_, B1_)

  const int lq = l >> 4;
#pragma unroll
  for (int fm = 0; fm < 4; ++fm)
#pragma unroll
    for (int n = 0; n < 4; ++n)
      for (int jj = 0; jj < 4; ++jj) {
        const int m = mtile * 128 + wm * 64 + fm * 16 + lq * 4 + jj;
        const int c = ntile * 256 + wn * 64 + n * 16 + lr;
        C[(size_t)m * DM + c] = acc[fm][n][jj];
      }
#undef RDA6
#undef RDB6
#undef MF6
#undef STG6
#undef VMW6
#undef PEND6
}

// ---------------- t_down split-K reduce -> masked SCAL*td into ha ext cols ----------------
__global__ void td_reduce(const float* __restrict__ part,
                          const int* __restrict__ idx,
                          u16* __restrict__ ha) {
  int i = blockIdx.x * blockDim.x + threadIdx.x;
  int m = i >> 7, c = i & 127;
  float s = 0.f;
#pragma unroll
  for (int k = 0; k < 8; ++k) s += part[(size_t)k * NTOK * 128 + i];
  u16 v = ((c >> 4) == idx[m]) ? f2bf(SCAL * s) : (u16)0;
  ha[(size_t)m * LDHA + 8192 + c] = v;
}

extern "C" void kernel_launch(void* const* d_in, const int* in_sizes, int n_in,
                              void* d_out, int out_size, void* d_ws, size_t ws_size,
                              hipStream_t stream) {
  const float* x  = (const float*)d_in[0];
  const float* wg = (const float*)d_in[1];
  const float* wu = (const float*)d_in[2];
  const float* wd = (const float*)d_in[3];
  const float* rw = (const float*)d_in[4];
  const float* rb = (const float*)d_in[5];
  const float* Ag = (const float*)d_in[6];
  const float* Bg = (const float*)d_in[7];
  const float* Au = (const float*)d_in[8];
  const float* Bu = (const float*)d_in[9];
  const float* Ad = (const float*)d_in[10];
  const float* Bd = (const float*)d_in[11];

  float* out      = (float*)d_out;
  float* out_rout = out + (size_t)NTOK * DM;
  float* out_ec   = out_rout + (size_t)NTOK * NEXP;

  char* ws = (char*)d_ws;
  size_t off = 0;
  auto take = [&](size_t b) { void* p = ws + off; off += (b + 255) & ~(size_t)255; return p; };
  u16*   xa   = (u16*)take((size_t)NTOK * LDXA * 2);
  u16*   ha   = (u16*)take((size_t)NTOK * LDHA * 2);
  u16*   wgx  = (u16*)take((size_t)DMLP * LDXA * 2);
  u16*   wux  = (u16*)take((size_t)DMLP * LDXA * 2);
  u16*   wdx  = (u16*)take((size_t)DM * LDHA * 2);
  u16*   Aab  = (u16*)take((size_t)256 * DM * 2);
  u16*   Adb  = (u16*)take((size_t)128 * DMLP * 2);
  float* tdp  = (float*)take((size_t)8 * NTOK * 128 * 4);
  int*   idx  = (int*)take((size_t)NTOK * 4);
  if (off > ws_size) return;

  // fused prep + router (one launch)
  prep_kernel<<<2048, 256, 0, stream>>>(wg, wu, wd, Ag, Au, Ad, Bg, Bu, Bd,
                                        wgx, wux, wdx, Aab, Adb,
                                        x, rw, rb, xa, idx, out_rout, out_ec);

  // t = xa @ [A_gate;A_up]^T -> masked SCAL*t into xa[:, 2048:2304]
  gemm_kernel<0><<<dim3(32, 2), 256, 0, stream>>>(xa, Aab, idx, xa);
  // gate/up fused (lora in K) + silu*mul -> ha[:, 0:8192]
  gemm_gu<<<1024, 512, 0, stream>>>(xa, wgx, wux, ha);
  // t_down partials: ha[:, :8192] @ A_down^T, 8-way K-split
  gemm_kernel<3><<<dim3(32, 8), 256, 0, stream>>>(ha, Adb, idx, tdp);
  td_reduce<<<NTOK * 128 / 256, 256, 0, stream>>>(tdp, idx, ha);
  // down (lora in K) -> f32 out
  gemm6<<<256, 512, 0, stream>>>(ha, wdx, out);
}

// Round 12
// 540.542 us; speedup vs baseline: 1.1414x; 1.0434x over previous
//
#include <hip/hip_runtime.h>
#include <stdint.h>

#define NTOK   4096
#define DM     2048
#define DMLP   8192
#define NEXP   8
#define NRANK  16
#define SCAL   2.0f

// Wide-A strides (LoRA folded into K):
//   xa: [4096, 2304]  = [x_bf16 | SCAL*t_gate_masked(128) | SCAL*t_up_masked(128)]
//   ha: [4096, 8320]  = [h_bf16 | SCAL*t_down_masked(128)]
#define LDXA 2304
#define LDHA 8320

typedef __bf16 bf16x8 __attribute__((ext_vector_type(8)));
typedef float  f32x4  __attribute__((ext_vector_type(4)));
typedef unsigned short u16;

__device__ __forceinline__ u16 f2bf(float f) {
  unsigned u = __float_as_uint(f);
  u += 0x7fffu + ((u >> 16) & 1u);   // RNE
  return (u16)(u >> 16);
}

__device__ __forceinline__ void gload_lds16(const void* g, void* l) {
  __builtin_amdgcn_global_load_lds((const __attribute__((address_space(1))) void*)g,
                                   (__attribute__((address_space(3))) void*)l, 16, 0, 0);
}

// ------- launch 1: router (blocks 0..1023) + small converts (Aab, Adb) -------
__global__ void prep_small(const float* __restrict__ x,
                           const float* __restrict__ rw,
                           const float* __restrict__ rb,
                           u16* __restrict__ xa,
                           int* __restrict__ idx,
                           float* __restrict__ out_rout,
                           float* __restrict__ out_ec,
                           const float* __restrict__ Ag,
                           const float* __restrict__ Au,
                           const float* __restrict__ Ad,
                           u16* __restrict__ Aab,
                           u16* __restrict__ Adb) {
  const int wave = threadIdx.x >> 6;
  const int lane = threadIdx.x & 63;
  const int m = blockIdx.x * 4 + wave;

  const float4* xrow = (const float4*)(x + (size_t)m * DM + lane * 32);
  float4 xv[8];
#pragma unroll
  for (int i = 0; i < 8; ++i) xv[i] = xrow[i];

  uint4 o[4];
  unsigned* op = (unsigned*)o;
#pragma unroll
  for (int i = 0; i < 8; ++i) {
    op[2*i]   = (unsigned)f2bf(xv[i].x) | ((unsigned)f2bf(xv[i].y) << 16);
    op[2*i+1] = (unsigned)f2bf(xv[i].z) | ((unsigned)f2bf(xv[i].w) << 16);
  }
  uint4* xdst = (uint4*)(xa + (size_t)m * LDXA + lane * 32);
#pragma unroll
  for (int i = 0; i < 4; ++i) xdst[i] = o[i];

  float lg[NEXP];
#pragma unroll
  for (int e = 0; e < NEXP; ++e) {
    const float4* wrow = (const float4*)(rw + (size_t)e * DM + lane * 32);
    float s = 0.f;
#pragma unroll
    for (int i = 0; i < 8; ++i) {
      float4 wv = wrow[i];
      s += xv[i].x*wv.x + xv[i].y*wv.y + xv[i].z*wv.z + xv[i].w*wv.w;
    }
#pragma unroll
    for (int off = 32; off > 0; off >>= 1) s += __shfl_xor(s, off, 64);
    lg[e] = s + rb[e];
  }

  float mx = lg[0];
#pragma unroll
  for (int e = 1; e < NEXP; ++e) mx = fmaxf(mx, lg[e]);
  float ex[NEXP], se = 0.f;
#pragma unroll
  for (int e = 0; e < NEXP; ++e) { ex[e] = expf(lg[e] - mx); se += ex[e]; }
  float inv = 1.f / se;
  int best = 0; float bv = lg[0];
#pragma unroll
  for (int e = 1; e < NEXP; ++e) if (lg[e] > bv) { bv = lg[e]; best = e; }

  if (lane == 0) {
    idx[m] = best;
#pragma unroll
    for (int e = 0; e < NEXP; ++e) {
      float r = ex[e] * inv;
      out_rout[(size_t)m * NEXP + e] = r;
      float hard = (e == best) ? 1.f : 0.f;
      out_ec[(size_t)m * NEXP + e] = (hard - r) + r;
    }
  }

  // small converts (grid-stride)
  const int gt = blockIdx.x * blockDim.x + threadIdx.x;
  const int gs = gridDim.x * blockDim.x;
  for (int i = gt; i < 256 * 512; i += gs) {
    float4 v = (i < 128 * 512) ? ((const float4*)Ag)[i] : ((const float4*)Au)[i - 128 * 512];
    ushort4 ov; ov.x = f2bf(v.x); ov.y = f2bf(v.y); ov.z = f2bf(v.z); ov.w = f2bf(v.w);
    ((ushort4*)Aab)[i] = ov;
  }
  for (int i = gt; i < 128 * 2048; i += gs) {
    float4 v = ((const float4*)Ad)[i];
    ushort4 ov; ov.x = f2bf(v.x); ov.y = f2bf(v.y); ov.z = f2bf(v.z); ov.w = f2bf(v.w);
    ((ushort4*)Adb)[i] = ov;
  }
}

// ------- launch 2: gemm0 (blocks 0..63, MFMA) fused with big weight prep -------
// gemm0: t = xa @ [A_gate;A_up]^T -> masked SCAL*t into xa[:, 2048:2304].
// Blocks >=64 grid-stride the wgx/wux/wdx main+ext builds (HBM-bound). The 64
// gemm0 blocks occupy 25% of CUs; fusing lets their MFMA hide under the prep
// stream instead of serializing two under-utilized launches.
__global__ __launch_bounds__(256, 2)
void gemm0_prep(const u16* __restrict__ A,
                const u16* __restrict__ B0,
                const int* __restrict__ idx,
                u16* __restrict__ Xout,
                const float* __restrict__ wg, const float* __restrict__ wu,
                const float* __restrict__ wd,
                const float* __restrict__ Bg, const float* __restrict__ Bu,
                const float* __restrict__ Bd,
                u16* __restrict__ wgx, u16* __restrict__ wux,
                u16* __restrict__ wdx)
{
  __shared__ u16 lds[16384];

  if (blockIdx.x < 64) {
    // ---- gemm0 path (128x128, K=2048, dbuf, swizzled) ----
    const int tid = threadIdx.x;
    const int w = tid >> 6;
    const int l = tid & 63;
    const int wm = w >> 1, wn = w & 1;
    const int mtile = (int)blockIdx.x >> 1;
    const int ntile = (int)blockIdx.x & 1;

    int srow[2];
    srow[0] = w * 16 + (l >> 2);
    srow[1] = 64 + srow[0];
    const int chunk = (l & 3) ^ ((srow[0] >> 1) & 3);
    const int scol = chunk * 8;

    const u16* aptr[2];
    const u16* bptr[2];
#pragma unroll
    for (int i = 0; i < 2; ++i) {
      aptr[i] = A + (size_t)(mtile * 128 + srow[i]) * LDXA + scol;
      bptr[i] = B0 + (size_t)(ntile * 128 + srow[i]) * 2048 + scol;
    }

    char* ldsc = (char*)lds;
    auto stage = [&](int buf, int kt) {
      const int kk = kt * 32;
      char* base = ldsc + buf * 16384;
#pragma unroll
      for (int i = 0; i < 2; ++i) {
        gload_lds16(aptr[i] + kk, base + i * 4096 + w * 1024);
        gload_lds16(bptr[i] + kk, base + 8192 + i * 4096 + w * 1024);
      }
    };

    f32x4 acc[4][4];
    f32x4 zf = {0.f, 0.f, 0.f, 0.f};
#pragma unroll
    for (int a = 0; a < 4; ++a)
#pragma unroll
      for (int b = 0; b < 4; ++b) acc[a][b] = zf;

    stage(0, 0);
    __syncthreads();

    const int kq   = l >> 4;
    const int arow = wm * 64 + (l & 15);
    const int brow = wn * 64 + (l & 15);
    const int axor = (kq ^ ((arow >> 1) & 3)) << 4;
    const int bxor = (kq ^ ((brow >> 1) & 3)) << 4;

    for (int kt = 0; kt < 64; ++kt) {
      const int buf = kt & 1;
      if (kt + 1 < 64) stage(buf ^ 1, kt + 1);
      const char* bA = ldsc + buf * 16384;
      const char* bB = bA + 8192;
      bf16x8 af[4], bfr[4];
#pragma unroll
      for (int fm = 0; fm < 4; ++fm)
        af[fm] = *(const bf16x8*)(bA + (arow + fm * 16) * 64 + axor);
#pragma unroll
      for (int fn = 0; fn < 4; ++fn)
        bfr[fn] = *(const bf16x8*)(bB + (brow + fn * 16) * 64 + bxor);
#pragma unroll
      for (int fm = 0; fm < 4; ++fm)
#pragma unroll
        for (int fn = 0; fn < 4; ++fn)
          acc[fm][fn] = __builtin_amdgcn_mfma_f32_16x16x32_bf16(af[fm], bfr[fn], acc[fm][fn], 0, 0, 0);
      __syncthreads();
    }

    const int lq = l >> 4;
    const int lr = l & 15;
#pragma unroll
    for (int fm = 0; fm < 4; ++fm)
#pragma unroll
      for (int fn = 0; fn < 4; ++fn)
        for (int j = 0; j < 4; ++j) {
          int m = mtile * 128 + wm * 64 + fm * 16 + lq * 4 + j;
          int c = ntile * 128 + wn * 64 + fn * 16 + lr;
          int e = idx[m];
          u16 v = (((c & 127) >> 4) == e) ? f2bf(SCAL * acc[fm][fn][j]) : (u16)0;
          Xout[(size_t)m * LDXA + 2048 + c] = v;
        }
    return;
  }

  // ---- big weight prep path (grid-stride over blocks 64..gridDim-1) ----
  const int gt = ((int)blockIdx.x - 64) * blockDim.x + threadIdx.x;
  const int gs = ((int)gridDim.x - 64) * blockDim.x;

  for (int i = gt; i < DMLP * 512; i += gs) {
    const int o = i >> 9, c = (i & 511) << 2;
    float4 v = ((const float4*)wg)[i];
    ushort4 ov; ov.x = f2bf(v.x); ov.y = f2bf(v.y); ov.z = f2bf(v.z); ov.w = f2bf(v.w);
    *(ushort4*)(wgx + (size_t)o * LDXA + c) = ov;
    v = ((const float4*)wu)[i];
    ov.x = f2bf(v.x); ov.y = f2bf(v.y); ov.z = f2bf(v.z); ov.w = f2bf(v.w);
    *(ushort4*)(wux + (size_t)o * LDXA + c) = ov;
  }
  for (int i = gt; i < DM * 2048; i += gs) {
    const int o = i >> 11, c = (i & 2047) << 2;
    float4 v = ((const float4*)wd)[i];
    ushort4 ov; ov.x = f2bf(v.x); ov.y = f2bf(v.y); ov.z = f2bf(v.z); ov.w = f2bf(v.w);
    *(ushort4*)(wdx + (size_t)o * LDHA + c) = ov;
  }
  for (int i = gt; i < DMLP * 256; i += gs) {
    const int o = i >> 8, c = i & 255;
    const int e = (c & 127) >> 4, r = c & 15;
    u16 vg = 0, vu = 0;
    if (c < 128) vg = f2bf(Bg[((size_t)e * DMLP + o) * NRANK + r]);
    else         vu = f2bf(Bu[((size_t)e * DMLP + o) * NRANK + r]);
    wgx[(size_t)o * LDXA + 2048 + c] = vg;
    wux[(size_t)o * LDXA + 2048 + c] = vu;
  }
  for (int i = gt; i < DM * 128; i += gs) {
    const int o = i >> 7, c = i & 127;
    const int e = c >> 4, r = c & 15;
    wdx[(size_t)o * LDHA + 8192 + c] = f2bf(Bd[((size_t)e * DM + o) * NRANK + r]);
  }
}

// ---------------- 128x128 GEMM core (MODE 3: t_down split-K partials) ----------------
__global__ __launch_bounds__(256, 2)
void gemm3_kernel(const u16* __restrict__ A,
                  const u16* __restrict__ B0,
                  void* __restrict__ Cout)
{
  __shared__ u16 lds[16384];

  const int tid = threadIdx.x;
  const int w = tid >> 6;
  const int l = tid & 63;
  const int wm = w >> 1, wn = w & 1;
  const int mtile = blockIdx.x;
  const int ks    = (int)blockIdx.y;
  const int kb0   = ks * 1024;

  int srow[2];
  srow[0] = w * 16 + (l >> 2);
  srow[1] = 64 + srow[0];
  const int chunk = (l & 3) ^ ((srow[0] >> 1) & 3);
  const int scol = chunk * 8;

  const u16* aptr[2];
  const u16* bptr[2];
#pragma unroll
  for (int i = 0; i < 2; ++i) {
    aptr[i] = A + (size_t)(mtile * 128 + srow[i]) * LDHA + kb0 + scol;
    bptr[i] = B0 + (size_t)srow[i] * 8192 + kb0 + scol;
  }

  char* ldsc = (char*)lds;
  auto stage = [&](int buf, int kt) {
    const int kk = kt * 32;
    char* base = ldsc + buf * 16384;
#pragma unroll
    for (int i = 0; i < 2; ++i) {
      gload_lds16(aptr[i] + kk, base + i * 4096 + w * 1024);
      gload_lds16(bptr[i] + kk, base + 8192 + i * 4096 + w * 1024);
    }
  };

  f32x4 acc[4][4];
  f32x4 zf = {0.f, 0.f, 0.f, 0.f};
#pragma unroll
  for (int a = 0; a < 4; ++a)
#pragma unroll
    for (int b = 0; b < 4; ++b) acc[a][b] = zf;

  stage(0, 0);
  __syncthreads();

  const int kq   = l >> 4;
  const int arow = wm * 64 + (l & 15);
  const int brow = wn * 64 + (l & 15);
  const int axor = (kq ^ ((arow >> 1) & 3)) << 4;
  const int bxor = (kq ^ ((brow >> 1) & 3)) << 4;

  for (int kt = 0; kt < 32; ++kt) {
    const int buf = kt & 1;
    if (kt + 1 < 32) stage(buf ^ 1, kt + 1);
    const char* bA = ldsc + buf * 16384;
    const char* bB = bA + 8192;
    bf16x8 af[4], bfr[4];
#pragma unroll
    for (int fm = 0; fm < 4; ++fm)
      af[fm] = *(const bf16x8*)(bA + (arow + fm * 16) * 64 + axor);
#pragma unroll
    for (int fn = 0; fn < 4; ++fn)
      bfr[fn] = *(const bf16x8*)(bB + (brow + fn * 16) * 64 + bxor);
#pragma unroll
    for (int fm = 0; fm < 4; ++fm)
#pragma unroll
      for (int fn = 0; fn < 4; ++fn)
        acc[fm][fn] = __builtin_amdgcn_mfma_f32_16x16x32_bf16(af[fm], bfr[fn], acc[fm][fn], 0, 0, 0);
    __syncthreads();
  }

  const int lq = l >> 4;
  const int lr = l & 15;
  float* P = (float*)Cout + (size_t)ks * NTOK * 128;
#pragma unroll
  for (int fm = 0; fm < 4; ++fm)
#pragma unroll
    for (int fn = 0; fn < 4; ++fn)
      for (int j = 0; j < 4; ++j) {
        int m = mtile * 128 + wm * 64 + fm * 16 + lq * 4 + j;
        int c = wn * 64 + fn * 16 + lr;
        P[(size_t)m * 128 + c] = acc[fm][fn][j];
      }
}

// ================= gemm_gu: 256x256 8-phase, register read-ahead (r8 proven) =====
__global__ __launch_bounds__(512, 2)
void gemm_gu(const u16* __restrict__ Ag,
             const u16* __restrict__ B0g,
             const u16* __restrict__ B1g,
             u16* __restrict__ H)
{
  constexpr int NKT = 36;
  __shared__ char L[131072];   // A: z*16384 (0..64K), B: 65536 + z*16384

  const int tid = threadIdx.x, w = tid >> 6, l = tid & 63;
  const int wm = w >> 2, wn = w & 3;
  const int bid = blockIdx.x;
  const int rr = bid >> 3;
  const int mtile = rr >> 3;
  const int ntile = (bid & 7) * 8 + (rr & 7);

  const u16 *agb0, *agb1, *bgb0, *bgb1;
  {
    int row0 = tid >> 2, row1 = 128 + row0;
    int lc = (tid & 3) ^ ((row0 >> 1) & 3);   // same for row0+128
    agb0 = Ag + (size_t)(mtile * 256 + row0) * LDXA + lc * 8;
    agb1 = Ag + (size_t)(mtile * 256 + row1) * LDXA + lc * 8;
    int c0 = ntile * 128 + ((row0 >> 5) << 4) + (row0 & 15);
    int c1 = ntile * 128 + ((row1 >> 5) << 4) + (row1 & 15);
    bgb0 = (((row0 >> 4) & 1) ? B1g : B0g) + (size_t)c0 * LDXA + lc * 8;
    bgb1 = (((row1 >> 4) & 1) ? B1g : B0g) + (size_t)c1 * LDXA + lc * 8;
  }
  const int sdst = w * 1024;

#define STGA(z, kt) { const int ko_ = ((kt) < NKT ? (kt) : NKT - 1) * 64 + ((z) & 1) * 32; \
    gload_lds16(agb0 + ko_, L + (z) * 16384 + sdst); \
    gload_lds16(agb1 + ko_, L + (z) * 16384 + 8192 + sdst); }
#define STGB(z, kt) { const int ko_ = ((kt) < NKT ? (kt) : NKT - 1) * 64 + ((z) & 1) * 32; \
    gload_lds16(bgb0 + ko_, L + 65536 + (z) * 16384 + sdst); \
    gload_lds16(bgb1 + ko_, L + 65536 + (z) * 16384 + 8192 + sdst); }

  const int lr = l & 15;
  const int kob = (((l >> 4) ^ ((lr >> 1) & 3)) << 4);
  const int abase = (wm * 128 + lr) * 64 + kob;
  const int bbase = (wn * 64 + lr) * 64 + kob;

  bf16x8 A0_[4], A1_[4], B0_[4], B1_[4];
#define RDA(S, z, qa) _Pragma("unroll") for (int f = 0; f < 4; ++f) \
    S[f] = *(const bf16x8*)(L + (z) * 16384 + abase + (qa) * 4096 + f * 1024);
#define RDB(S, z) _Pragma("unroll") for (int f = 0; f < 4; ++f) \
    S[f] = *(const bf16x8*)(L + 65536 + (z) * 16384 + bbase + f * 1024);

  f32x4 acc[8][4];
  f32x4 zf = {0.f, 0.f, 0.f, 0.f};
#pragma unroll
  for (int a = 0; a < 8; ++a)
#pragma unroll
    for (int b = 0; b < 4; ++b) acc[a][b] = zf;

#define MF(qa, AS, BS) \
  __builtin_amdgcn_s_setprio(1); \
  _Pragma("unroll") for (int f = 0; f < 4; ++f) \
    _Pragma("unroll") for (int n = 0; n < 4; ++n) \
      acc[(qa) * 4 + f][n] = __builtin_amdgcn_mfma_f32_16x16x32_bf16(AS[f], BS[n], acc[(qa) * 4 + f][n], 0, 0, 0); \
  __builtin_amdgcn_s_setprio(0);

#define VMW  { asm volatile("s_waitcnt vmcnt(6)" ::: "memory"); __builtin_amdgcn_sched_barrier(0); }
#define PEND { __builtin_amdgcn_sched_barrier(0); __builtin_amdgcn_s_barrier(); __builtin_amdgcn_sched_barrier(0); }

  // prologue: stage z0<-kt0s0, z1<-kt0s1, z2<-kt1s0 (FIFO order); vm(6); BARRIER
  // (z0 globally valid); then pre-read z0.
  STGA(0, 0) STGB(0, 0)
  STGA(1, 0) STGB(1, 0)
  STGA(2, 1) STGB(2, 1)
  VMW
  PEND
  RDB(B0_, 0) RDA(A0_, 0, 0)

  for (int it = 0; it < NKT / 2; ++it) {
    const int k1 = 2 * it + 1, k2 = 2 * it + 2, k3 = 2 * it + 3;
    // P0: compute z0.qa0
    STGA(3, k1)
    RDA(A1_, 0, 1)
    MF(0, A0_, B0_)  VMW  PEND
    // P1: compute z0.qa1
    STGB(3, k1)
    RDB(B1_, 1) RDA(A0_, 1, 0)
    MF(1, A1_, B0_)  PEND
    // P2: compute z1.qa0
    STGA(0, k2)
    RDA(A1_, 1, 1)
    MF(0, A0_, B1_)  VMW  PEND
    // P3: compute z1.qa1
    STGB(0, k2)
    RDB(B0_, 2) RDA(A0_, 2, 0)
    MF(1, A1_, B1_)  PEND
    // P4: compute z2.qa0
    STGA(1, k2)
    RDA(A1_, 2, 1)
    MF(0, A0_, B0_)  VMW  PEND
    // P5: compute z2.qa1
    STGB(1, k2)
    RDB(B1_, 3) RDA(A0_, 3, 0)
    MF(1, A1_, B0_)  PEND
    // P6: compute z3.qa0
    STGA(2, k3)
    RDA(A1_, 3, 1)
    MF(0, A0_, B1_)  VMW  PEND
    // P7: compute z3.qa1
    STGB(2, k3)
    RDB(B0_, 0) RDA(A0_, 0, 0)
    MF(1, A1_, B1_)  PEND
  }

  const int lq = l >> 4;
#pragma unroll
  for (int fm = 0; fm < 8; ++fm)
    for (int jj = 0; jj < 4; ++jj) {
      const int m = mtile * 256 + wm * 128 + fm * 16 + lq * 4 + jj;
#pragma unroll
      for (int p = 0; p < 2; ++p) {
        float g = acc[fm][2 * p][jj];
        float u = acc[fm][2 * p + 1][jj];
        float e = __builtin_amdgcn_exp2f(g * -1.44269504089f);
        float h = g * __builtin_amdgcn_rcpf(1.f + e) * u;
        const int c = ntile * 128 + (wn * 2 + p) * 16 + lr;
        H[(size_t)m * LDHA + c] = f2bf(h);
      }
    }
#undef RDA
#undef RDB
#undef MF
#undef STGA
#undef STGB
#undef VMW
#undef PEND
}

// ================= gemm6: down-proj 128x256, ring-of-6 slots (r8 proven) =========
__global__ __launch_bounds__(512, 2)
void gemm6(const u16* __restrict__ Ag,
           const u16* __restrict__ Bg,
           float* __restrict__ C)
{
  __shared__ char L[147456];
  const int tid = threadIdx.x, w = tid >> 6, l = tid & 63;
  const int wm = w >> 2, wn = w & 3;   // wave tile 64m x 64n
  const int bid = blockIdx.x;
  const int swz = (bid & 7) * 32 + (bid >> 3);
  const int mtile = swz >> 3;
  const int ntile = swz & 7;

  const u16 *agb0, *bgb0, *bgb1;
  {
    int row0 = tid >> 2;
    int lc = (tid & 3) ^ ((row0 >> 1) & 3);
    agb0 = Ag + (size_t)(mtile * 128 + row0) * LDHA + lc * 8;
    bgb0 = Bg + (size_t)(ntile * 256 + row0) * LDHA + lc * 8;
    bgb1 = Bg + (size_t)(ntile * 256 + 128 + row0) * LDHA + lc * 8;
  }
  const int sdst = w * 1024;

#define STG6(z, g) { const int gg_ = (g) < 260 ? (g) : 259; \
    const int ko_ = (gg_ >> 1) * 64 + (gg_ & 1) * 32; \
    gload_lds16(agb0 + ko_, L + (z) * 24576 + sdst); \
    gload_lds16(bgb0 + ko_, L + (z) * 24576 + 8192 + sdst); \
    gload_lds16(bgb1 + ko_, L + (z) * 24576 + 16384 + sdst); }

  const int lr = l & 15;
  const int kob = (((l >> 4) ^ ((lr >> 1) & 3)) << 4);
  const int abase = (wm * 64 + lr) * 64 + kob;
  const int bbase = (wn * 64 + lr) * 64 + kob;

  bf16x8 A0_[4], A1_[4], B0_[4], B1_[4];
#define RDA6(S, z) _Pragma("unroll") for (int f = 0; f < 4; ++f) \
    S[f] = *(const bf16x8*)(L + (z) * 24576 + abase + f * 1024);
#define RDB6(S, z) _Pragma("unroll") for (int f = 0; f < 4; ++f) \
    S[f] = *(const bf16x8*)(L + (z) * 24576 + 8192 + bbase + f * 1024);

  f32x4 acc[4][4];
  f32x4 zf = {0.f, 0.f, 0.f, 0.f};
#pragma unroll
  for (int a = 0; a < 4; ++a)
#pragma unroll
    for (int b = 0; b < 4; ++b) acc[a][b] = zf;

#define MF6(AS, BS) \
  __builtin_amdgcn_s_setprio(1); \
  _Pragma("unroll") for (int f = 0; f < 4; ++f) \
    _Pragma("unroll") for (int n = 0; n < 4; ++n) \
      acc[f][n] = __builtin_amdgcn_mfma_f32_16x16x32_bf16(AS[f], BS[n], acc[f][n], 0, 0, 0); \
  __builtin_amdgcn_s_setprio(0);

#define VMW6 { asm volatile("s_waitcnt vmcnt(6)" ::: "memory"); __builtin_amdgcn_sched_barrier(0); }
#define PEND6 { __builtin_amdgcn_sched_barrier(0); __builtin_amdgcn_s_barrier(); __builtin_amdgcn_sched_barrier(0); }

  STG6(0, 0) STG6(1, 1) STG6(2, 2) STG6(3, 3)
  VMW6
  PEND6
  RDB6(B0_, 0) RDA6(A0_, 0)

  for (int it = 0; it < 43; ++it) {
    const int g4 = it * 6 + 4;
    STG6(4, g4)      RDB6(B1_, 1) RDA6(A1_, 1)  MF6(A0_, B0_)  VMW6  PEND6
    STG6(5, g4 + 1)  RDB6(B0_, 2) RDA6(A0_, 2)  MF6(A1_, B1_)  VMW6  PEND6
    STG6(0, g4 + 2)  RDB6(B1_, 3) RDA6(A1_, 3)  MF6(A0_, B0_)  VMW6  PEND6
    STG6(1, g4 + 3)  RDB6(B0_, 4) RDA6(A0_, 4)  MF6(A1_, B1_)  VMW6  PEND6
    STG6(2, g4 + 4)  RDB6(B1_, 5) RDA6(A1_, 5)  MF6(A0_, B0_)  VMW6  PEND6
    STG6(3, g4 + 5)  RDB6(B0_, 0) RDA6(A0_, 0)  MF6(A1_, B1_)  VMW6  PEND6
  }
  RDB6(B1_, 1) RDA6(A1_, 1)
  MF6(A0_, B0_)
  MF6(A1_, B1_)

  const int lq = l >> 4;
#pragma unroll
  for (int fm = 0; fm < 4; ++fm)
#pragma unroll
    for (int n = 0; n < 4; ++n)
      for (int jj = 0; jj < 4; ++jj) {
        const int m = mtile * 128 + wm * 64 + fm * 16 + lq * 4 + jj;
        const int c = ntile * 256 + wn * 64 + n * 16 + lr;
        C[(size_t)m * DM + c] = acc[fm][n][jj];
      }
#undef RDA6
#undef RDB6
#undef MF6
#undef STG6
#undef VMW6
#undef PEND6
}

// ---------------- t_down split-K reduce -> masked SCAL*td into ha ext cols ----------------
__global__ void td_reduce(const float* __restrict__ part,
                          const int* __restrict__ idx,
                          u16* __restrict__ ha) {
  int i = blockIdx.x * blockDim.x + threadIdx.x;
  int m = i >> 7, c = i & 127;
  float s = 0.f;
#pragma unroll
  for (int k = 0; k < 8; ++k) s += part[(size_t)k * NTOK * 128 + i];
  u16 v = ((c >> 4) == idx[m]) ? f2bf(SCAL * s) : (u16)0;
  ha[(size_t)m * LDHA + 8192 + c] = v;
}

extern "C" void kernel_launch(void* const* d_in, const int* in_sizes, int n_in,
                              void* d_out, int out_size, void* d_ws, size_t ws_size,
                              hipStream_t stream) {
  const float* x  = (const float*)d_in[0];
  const float* wg = (const float*)d_in[1];
  const float* wu = (const float*)d_in[2];
  const float* wd = (const float*)d_in[3];
  const float* rw = (const float*)d_in[4];
  const float* rb = (const float*)d_in[5];
  const float* Ag = (const float*)d_in[6];
  const float* Bg = (const float*)d_in[7];
  const float* Au = (const float*)d_in[8];
  const float* Bu = (const float*)d_in[9];
  const float* Ad = (const float*)d_in[10];
  const float* Bd = (const float*)d_in[11];

  float* out      = (float*)d_out;
  float* out_rout = out + (size_t)NTOK * DM;
  float* out_ec   = out_rout + (size_t)NTOK * NEXP;

  char* ws = (char*)d_ws;
  size_t off = 0;
  auto take = [&](size_t b) { void* p = ws + off; off += (b + 255) & ~(size_t)255; return p; };
  u16*   xa   = (u16*)take((size_t)NTOK * LDXA * 2);
  u16*   ha   = (u16*)take((size_t)NTOK * LDHA * 2);
  u16*   wgx  = (u16*)take((size_t)DMLP * LDXA * 2);
  u16*   wux  = (u16*)take((size_t)DMLP * LDXA * 2);
  u16*   wdx  = (u16*)take((size_t)DM * LDHA * 2);
  u16*   Aab  = (u16*)take((size_t)256 * DM * 2);
  u16*   Adb  = (u16*)take((size_t)128 * DMLP * 2);
  float* tdp  = (float*)take((size_t)8 * NTOK * 128 * 4);
  int*   idx  = (int*)take((size_t)NTOK * 4);
  if (off > ws_size) return;

  // launch 1: router + small converts (Aab, Adb)
  prep_small<<<NTOK / 4, 256, 0, stream>>>(x, rw, rb, xa, idx, out_rout, out_ec,
                                           Ag, Au, Ad, Aab, Adb);
  // launch 2: gemm0 (64 blocks) fused with big weight prep (2048 blocks)
  gemm0_prep<<<2112, 256, 0, stream>>>(xa, Aab, idx, xa,
                                       wg, wu, wd, Bg, Bu, Bd, wgx, wux, wdx);
  // gate/up fused (lora in K) + silu*mul -> ha[:, 0:8192]
  gemm_gu<<<1024, 512, 0, stream>>>(xa, wgx, wux, ha);
  // t_down partials: ha[:, :8192] @ A_down^T, 8-way K-split
  gemm3_kernel<<<dim3(32, 8), 256, 0, stream>>>(ha, Adb, tdp);
  td_reduce<<<NTOK * 128 / 256, 256, 0, stream>>>(tdp, idx, ha);
  // down (lora in K) -> f32 out
  gemm6<<<256, 512, 0, stream>>>(ha, wdx, out);
}